// Round 3
// baseline (386.320 us; speedup 1.0000x reference)
//
#include <hip/hip_runtime.h>
#include <hip/hip_bf16.h>
#include <math.h>

typedef __attribute__((ext_vector_type(4))) float f32x4;
typedef __attribute__((ext_vector_type(8))) short bf16x8;

#define DEVI __device__ __forceinline__
#define GLBP(p) ((const __attribute__((address_space(1))) void*)(p))
#define LDSP(p) ((__attribute__((address_space(3))) void*)(p))

DEVI unsigned short f2b(float x) {
    __hip_bfloat16 b = __float2bfloat16(x);
    return *reinterpret_cast<unsigned short*>(&b);
}

// ---------------- cast f32 -> bf16, vectorized ----------------
__global__ void cast_f32_to_bf16(const float* __restrict__ in,
                                 unsigned short* __restrict__ out, int n) {
    int stride = gridDim.x * blockDim.x;
    for (int i = blockIdx.x * blockDim.x + threadIdx.x; i * 4 < n; i += stride) {
        float4 v = reinterpret_cast<const float4*>(in)[i];
        ushort4 o;
        o.x = f2b(v.x); o.y = f2b(v.y); o.z = f2b(v.z); o.w = f2b(v.w);
        reinterpret_cast<ushort4*>(out)[i] = o;
    }
}

// ------------- transpose+cast: f32 [R][C] -> bf16 [C][R] -------------
__global__ void transpose_cast(const float* __restrict__ in,
                               unsigned short* __restrict__ out, int R, int C) {
    __shared__ float t[32][33];
    int bc = blockIdx.x * 32, br = blockIdx.y * 32;
    int x = threadIdx.x, y = threadIdx.y;   // block (32,8)
#pragma unroll
    for (int j = 0; j < 32; j += 8)
        t[y + j][x] = in[(size_t)(br + y + j) * C + bc + x];
    __syncthreads();
#pragma unroll
    for (int j = 0; j < 32; j += 8)
        out[(size_t)(bc + y + j) * R + br + x] = f2b(t[x][y + j]);
}

// ------------- GEMM: C[M,N] = A[M,K] * B[N,K]^T (bf16 in, bf16/f32 out) -------------
// m97 structure: 128x128 tile, BK=32, 4 waves, 4x4 16x16x32 MFMA frags/wave,
// global_load_lds width-16 staging, 2 barriers per K-step.
template<int OUTF32>
__global__ __launch_bounds__(256, 2)
void gemm_bt(const unsigned short* __restrict__ A,
             const unsigned short* __restrict__ B,
             void* __restrict__ Cp, const float* __restrict__ bias,
             int M, int N, int K) {
    __shared__ unsigned short As[128 * 32];
    __shared__ unsigned short Bs[128 * 32];
    const int tid  = threadIdx.x;
    const int wave = tid >> 6;
    const int lane = tid & 63;
    const int nbn  = N >> 7;
    const int bm   = blockIdx.x / nbn;
    const int bn   = blockIdx.x - bm * nbn;

    const int lr  = lane & 15;
    const int lk8 = (lane >> 4) << 3;
    const int wr  = (wave >> 1) * 64;
    const int wc  = (wave & 1) * 64;

    const unsigned short* ag = A + (size_t)(bm * 128 + (tid >> 2)) * K + ((tid & 3) << 3);
    const unsigned short* bg = B + (size_t)(bn * 128 + (tid >> 2)) * K + ((tid & 3) << 3);
    unsigned short* asd = As + wave * 512;   // wave-uniform LDS dest
    unsigned short* bsd = Bs + wave * 512;

    f32x4 acc[4][4];
#pragma unroll
    for (int m = 0; m < 4; ++m)
#pragma unroll
        for (int n = 0; n < 4; ++n)
            acc[m][n] = (f32x4){0.f, 0.f, 0.f, 0.f};

    for (int k0 = 0; k0 < K; k0 += 32) {
        __builtin_amdgcn_global_load_lds(GLBP(ag + k0),                    LDSP(asd),        16, 0, 0);
        __builtin_amdgcn_global_load_lds(GLBP(ag + (size_t)64 * K + k0),   LDSP(asd + 2048), 16, 0, 0);
        __builtin_amdgcn_global_load_lds(GLBP(bg + k0),                    LDSP(bsd),        16, 0, 0);
        __builtin_amdgcn_global_load_lds(GLBP(bg + (size_t)64 * K + k0),   LDSP(bsd + 2048), 16, 0, 0);
        __syncthreads();
        bf16x8 af[4], bfr[4];
#pragma unroll
        for (int m = 0; m < 4; ++m)
            af[m] = *reinterpret_cast<const bf16x8*>(&As[(wr + m * 16 + lr) * 32 + lk8]);
#pragma unroll
        for (int n = 0; n < 4; ++n)
            bfr[n] = *reinterpret_cast<const bf16x8*>(&Bs[(wc + n * 16 + lr) * 32 + lk8]);
#pragma unroll
        for (int m = 0; m < 4; ++m)
#pragma unroll
            for (int n = 0; n < 4; ++n)
                acc[m][n] = __builtin_amdgcn_mfma_f32_16x16x32_bf16(af[m], bfr[n], acc[m][n], 0, 0, 0);
        __syncthreads();
    }

    const int rb = (lane >> 4) << 2;
    if (OUTF32) {
        float* C = reinterpret_cast<float*>(Cp);
#pragma unroll
        for (int m = 0; m < 4; ++m)
#pragma unroll
            for (int n = 0; n < 4; ++n) {
                const int col = bn * 128 + wc + n * 16 + lr;
                const float bv = bias[col];
#pragma unroll
                for (int r = 0; r < 4; ++r) {
                    const int row = bm * 128 + wr + m * 16 + rb + r;
                    C[(size_t)row * N + col] = acc[m][n][r] + bv;
                }
            }
    } else {
        unsigned short* C = reinterpret_cast<unsigned short*>(Cp);
#pragma unroll
        for (int m = 0; m < 4; ++m)
#pragma unroll
            for (int n = 0; n < 4; ++n) {
                const int col = bn * 128 + wc + n * 16 + lr;
#pragma unroll
                for (int r = 0; r < 4; ++r) {
                    const int row = bm * 128 + wr + m * 16 + rb + r;
                    C[(size_t)row * N + col] = f2b(acc[m][n][r]);
                }
            }
    }
}

// ------------- fused flash attention with key-length masking (v2) -------------
// grid: (B*H) * (N/64), XCD-swizzled.  block 256 = 4 waves, 16 q-rows/wave.
// Changes vs v1 (theory: bank conflicts were 30% of time; K LDS-staging is
// pure overhead since KV slice L2-fits):
//  - K fragments load DIRECT from global (no Kl LDS tile at all).
//  - V transpose staging reassigned: dseg wave-uniform, key=lane ->
//    per-store addr = const + lane -> all 32 banks, 2-way word-pair = free.
//  - P barrier removed (Pl[wave] is per-wave private; same-wave lgkm dep).
__global__ __launch_bounds__(256, 2)
void attn_fused(const unsigned short* __restrict__ Q,   // [8192][1024]
                const unsigned short* __restrict__ KV,  // [8192][2048] (k | v)
                const int* __restrict__ lengths,
                unsigned short* __restrict__ O) {       // [8192][1024]
    __shared__ unsigned short Vt[64 * 72];      // [d][key], stride 72
    __shared__ unsigned short Pl[4][16 * 72];   // per-wave [q][key], stride 72

    const int tid  = threadIdx.x;
    const int wave = tid >> 6;
    const int lane = tid & 63;
    // XCD swizzle: the 16 qt-blocks sharing one (b,h)'s KV land on one XCD.
    const int swz = (blockIdx.x & 7) * 256 + (blockIdx.x >> 3);
    const int qt = swz & 15;
    const int bh = swz >> 4;
    const int b  = bh >> 4;
    const int h  = bh & 15;
    const int L  = lengths[b];

    const int lr  = lane & 15;
    const int g   = lane >> 4;
    const int lk8 = g << 3;     // 0,8,16,24
    const int rb  = g << 2;     // 0,4,8,12

    const size_t kvbase = (size_t)(b * 1024) * 2048 + h * 64;

    // Q fragments (A-operand: row=lane&15, k=(lane>>4)*8+j within 32-slice)
    const size_t qrow = (size_t)(b * 1024 + qt * 64 + wave * 16 + lr);
    bf16x8 qf[2];
    qf[0] = *reinterpret_cast<const bf16x8*>(&Q[qrow * 1024 + h * 64 + lk8]);
    qf[1] = *reinterpret_cast<const bf16x8*>(&Q[qrow * 1024 + h * 64 + 32 + lk8]);

    f32x4 oacc[4];
#pragma unroll
    for (int nd = 0; nd < 4; ++nd) oacc[nd] = (f32x4){0.f, 0.f, 0.f, 0.f};
    float mrun[4] = {-3.0e38f, -3.0e38f, -3.0e38f, -3.0e38f};
    float lrun[4] = {0.f, 0.f, 0.f, 0.f};

    const int ntiles = (L + 63) >> 6;
    for (int t = 0; t < ntiles; ++t) {
        const int j0 = t * 64;
        __syncthreads();   // all PV reads of Vt[t-1] done before overwrite

        // ---- V stage: global -> reg (issued early, hides under QK^T) ----
        // rep r: dseg block = (r*4+wave)*8 (wave-uniform), key = lane.
        bf16x8 vv[2];
#pragma unroll
        for (int rep = 0; rep < 2; ++rep) {
            const int dseg = ((rep * 4 + wave) & 7) << 3;
            vv[rep] = *reinterpret_cast<const bf16x8*>(
                &KV[kvbase + (size_t)(j0 + lane) * 2048 + 1024 + dseg]);
        }

        // ---- S = Q K^T, K fragments direct from global ----
        f32x4 sacc[4];
#pragma unroll
        for (int n = 0; n < 4; ++n) sacc[n] = (f32x4){0.f, 0.f, 0.f, 0.f};
#pragma unroll
        for (int n = 0; n < 4; ++n) {
            const unsigned short* kp = &KV[kvbase + (size_t)(j0 + n * 16 + lr) * 2048 + lk8];
            bf16x8 kf0 = *reinterpret_cast<const bf16x8*>(kp);
            bf16x8 kf1 = *reinterpret_cast<const bf16x8*>(kp + 32);
            sacc[n] = __builtin_amdgcn_mfma_f32_16x16x32_bf16(qf[0], kf0, sacc[n], 0, 0, 0);
            sacc[n] = __builtin_amdgcn_mfma_f32_16x16x32_bf16(qf[1], kf1, sacc[n], 0, 0, 0);
        }

        // ---- V transpose writes: per-instr addr = const + lane (conflict-free) ----
#pragma unroll
        for (int rep = 0; rep < 2; ++rep) {
            const int dseg = ((rep * 4 + wave) & 7) << 3;
#pragma unroll
            for (int j = 0; j < 8; ++j)
                Vt[(dseg + j) * 72 + lane] = (unsigned short)vv[rep][j];
        }

        // ---- scale + mask ----
        float sv[4][4];
#pragma unroll
        for (int n = 0; n < 4; ++n)
#pragma unroll
            for (int r = 0; r < 4; ++r) {
                const int key = j0 + n * 16 + lr;
                sv[n][r] = (key < L) ? sacc[n][r] * 0.125f : -3.0e38f;
            }

        // ---- online softmax (row r of 16-lane group) ----
        float alpha[4], psum[4];
#pragma unroll
        for (int r = 0; r < 4; ++r) {
            float tm = fmaxf(fmaxf(sv[0][r], sv[1][r]), fmaxf(sv[2][r], sv[3][r]));
#pragma unroll
            for (int off = 1; off < 16; off <<= 1)
                tm = fmaxf(tm, __shfl_xor(tm, off));
            const float mn = fmaxf(mrun[r], tm);
            alpha[r] = __expf(mrun[r] - mn);
            mrun[r] = mn;
            psum[r] = 0.f;
        }
        float pv[4][4];
#pragma unroll
        for (int n = 0; n < 4; ++n)
#pragma unroll
            for (int r = 0; r < 4; ++r) {
                const float p = __expf(sv[n][r] - mrun[r]);
                pv[n][r] = p;
                psum[r] += p;
            }
#pragma unroll
        for (int r = 0; r < 4; ++r) {
#pragma unroll
            for (int off = 1; off < 16; off <<= 1)
                psum[r] += __shfl_xor(psum[r], off);
            lrun[r] = lrun[r] * alpha[r] + psum[r];
        }
#pragma unroll
        for (int nd = 0; nd < 4; ++nd)
#pragma unroll
            for (int r = 0; r < 4; ++r)
                oacc[nd][r] *= alpha[r];

        // ---- P -> per-wave LDS (no barrier needed: same-wave dep) ----
#pragma unroll
        for (int n = 0; n < 4; ++n)
#pragma unroll
            for (int r = 0; r < 4; ++r)
                Pl[wave][(rb + r) * 72 + n * 16 + lr] = f2b(pv[n][r]);

        __syncthreads();   // Vt fully staged by all waves before PV

        // ---- O += P V ----
        bf16x8 pf0 = *reinterpret_cast<const bf16x8*>(&Pl[wave][lr * 72 + lk8]);
        bf16x8 pf1 = *reinterpret_cast<const bf16x8*>(&Pl[wave][lr * 72 + 32 + lk8]);
#pragma unroll
        for (int nd = 0; nd < 4; ++nd) {
            bf16x8 vf0 = *reinterpret_cast<const bf16x8*>(&Vt[(nd * 16 + lr) * 72 + lk8]);
            bf16x8 vf1 = *reinterpret_cast<const bf16x8*>(&Vt[(nd * 16 + lr) * 72 + 32 + lk8]);
            oacc[nd] = __builtin_amdgcn_mfma_f32_16x16x32_bf16(pf0, vf0, oacc[nd], 0, 0, 0);
            oacc[nd] = __builtin_amdgcn_mfma_f32_16x16x32_bf16(pf1, vf1, oacc[nd], 0, 0, 0);
        }
    }

    // ---- normalize + write ----
    const size_t orow = (size_t)(b * 1024 + qt * 64 + wave * 16);
#pragma unroll
    for (int r = 0; r < 4; ++r) {
        const float inv = 1.0f / lrun[r];
#pragma unroll
        for (int nd = 0; nd < 4; ++nd)
            O[(orow + rb + r) * 1024 + h * 64 + nd * 16 + lr] = f2b(oacc[nd][r] * inv);
    }
}

extern "C" void kernel_launch(void* const* d_in, const int* in_sizes, int n_in,
                              void* d_out, int out_size, void* d_ws, size_t ws_size,
                              hipStream_t stream) {
    const float* x    = (const float*)d_in[0];
    const float* ctx  = (const float*)d_in[1];
    const int*   len  = (const int*)d_in[2];
    const float* Wq   = (const float*)d_in[3];
    const float* Wkv  = (const float*)d_in[4];
    const float* Wout = (const float*)d_in[5];
    const float* bout = (const float*)d_in[6];
    float* out = (float*)d_out;

    char* w = (char*)d_ws;
    unsigned short* xb   = (unsigned short*)w; w += (size_t)8192 * 1024 * 2;
    unsigned short* cb   = (unsigned short*)w; w += (size_t)8192 * 1024 * 2;
    unsigned short* qb   = (unsigned short*)w; w += (size_t)8192 * 1024 * 2;
    unsigned short* kvb  = (unsigned short*)w; w += (size_t)8192 * 2048 * 2;
    unsigned short* aob  = (unsigned short*)w; w += (size_t)8192 * 1024 * 2;
    unsigned short* wqt  = (unsigned short*)w; w += (size_t)1024 * 1024 * 2;
    unsigned short* wkvt = (unsigned short*)w; w += (size_t)2048 * 1024 * 2;
    unsigned short* wot  = (unsigned short*)w; w += (size_t)1024 * 1024 * 2;

    cast_f32_to_bf16<<<2048, 256, 0, stream>>>(x,   xb, 8192 * 1024);
    cast_f32_to_bf16<<<2048, 256, 0, stream>>>(ctx, cb, 8192 * 1024);
    dim3 tb(32, 8);
    transpose_cast<<<dim3(32, 32), tb, 0, stream>>>(Wq,   wqt,  1024, 1024);
    transpose_cast<<<dim3(64, 32), tb, 0, stream>>>(Wkv,  wkvt, 1024, 2048);
    transpose_cast<<<dim3(32, 32), tb, 0, stream>>>(Wout, wot,  1024, 1024);

    gemm_bt<0><<<512,  256, 0, stream>>>(xb, wqt,  (void*)qb,  nullptr, 8192, 1024, 1024);
    gemm_bt<0><<<1024, 256, 0, stream>>>(cb, wkvt, (void*)kvb, nullptr, 8192, 2048, 1024);
    attn_fused<<<2048, 256, 0, stream>>>(qb, kvb, len, aob);
    gemm_bt<1><<<512,  256, 0, stream>>>(aob, wot, (void*)out, bout, 8192, 1024, 1024);
}

// Round 4
// 371.820 us; speedup vs baseline: 1.0390x; 1.0390x over previous
//
#include <hip/hip_runtime.h>
#include <hip/hip_bf16.h>
#include <math.h>

typedef __attribute__((ext_vector_type(4))) float f32x4;
typedef __attribute__((ext_vector_type(8))) short bf16x8;

#define DEVI __device__ __forceinline__
#define GLBP(p) ((const __attribute__((address_space(1))) void*)(p))
#define LDSP(p) ((__attribute__((address_space(3))) void*)(p))

DEVI unsigned short f2b(float x) {
    __hip_bfloat16 b = __float2bfloat16(x);
    return *reinterpret_cast<unsigned short*>(&b);
}

// ---------------- cast f32 -> bf16, vectorized ----------------
__global__ void cast_f32_to_bf16(const float* __restrict__ in,
                                 unsigned short* __restrict__ out, int n) {
    int stride = gridDim.x * blockDim.x;
    for (int i = blockIdx.x * blockDim.x + threadIdx.x; i * 4 < n; i += stride) {
        float4 v = reinterpret_cast<const float4*>(in)[i];
        ushort4 o;
        o.x = f2b(v.x); o.y = f2b(v.y); o.z = f2b(v.z); o.w = f2b(v.w);
        reinterpret_cast<ushort4*>(out)[i] = o;
    }
}

// ------------- transpose+cast: f32 [R][C] -> bf16 [C][R] -------------
__global__ void transpose_cast(const float* __restrict__ in,
                               unsigned short* __restrict__ out, int R, int C) {
    __shared__ float t[32][33];
    int bc = blockIdx.x * 32, br = blockIdx.y * 32;
    int x = threadIdx.x, y = threadIdx.y;   // block (32,8)
#pragma unroll
    for (int j = 0; j < 32; j += 8)
        t[y + j][x] = in[(size_t)(br + y + j) * C + bc + x];
    __syncthreads();
#pragma unroll
    for (int j = 0; j < 32; j += 8)
        out[(size_t)(bc + y + j) * R + br + x] = f2b(t[x][y + j]);
}

// ------------- GEMM: C[M,N] = A[M,K] * B[N,K]^T (bf16 in, bf16/f32 out) -------------
// m97 structure: 128x128 tile, BK=32, 4 waves, 4x4 16x16x32 MFMA frags/wave,
// global_load_lds width-16 staging, 2 barriers per K-step.
template<int OUTF32>
__global__ __launch_bounds__(256, 2)
void gemm_bt(const unsigned short* __restrict__ A,
             const unsigned short* __restrict__ B,
             void* __restrict__ Cp, const float* __restrict__ bias,
             int M, int N, int K) {
    __shared__ unsigned short As[128 * 32];
    __shared__ unsigned short Bs[128 * 32];
    const int tid  = threadIdx.x;
    const int wave = tid >> 6;
    const int lane = tid & 63;
    const int nbn  = N >> 7;
    const int bm   = blockIdx.x / nbn;
    const int bn   = blockIdx.x - bm * nbn;

    const int lr  = lane & 15;
    const int lk8 = (lane >> 4) << 3;
    const int wr  = (wave >> 1) * 64;
    const int wc  = (wave & 1) * 64;

    const unsigned short* ag = A + (size_t)(bm * 128 + (tid >> 2)) * K + ((tid & 3) << 3);
    const unsigned short* bg = B + (size_t)(bn * 128 + (tid >> 2)) * K + ((tid & 3) << 3);
    unsigned short* asd = As + wave * 512;   // wave-uniform LDS dest
    unsigned short* bsd = Bs + wave * 512;

    f32x4 acc[4][4];
#pragma unroll
    for (int m = 0; m < 4; ++m)
#pragma unroll
        for (int n = 0; n < 4; ++n)
            acc[m][n] = (f32x4){0.f, 0.f, 0.f, 0.f};

    for (int k0 = 0; k0 < K; k0 += 32) {
        __builtin_amdgcn_global_load_lds(GLBP(ag + k0),                    LDSP(asd),        16, 0, 0);
        __builtin_amdgcn_global_load_lds(GLBP(ag + (size_t)64 * K + k0),   LDSP(asd + 2048), 16, 0, 0);
        __builtin_amdgcn_global_load_lds(GLBP(bg + k0),                    LDSP(bsd),        16, 0, 0);
        __builtin_amdgcn_global_load_lds(GLBP(bg + (size_t)64 * K + k0),   LDSP(bsd + 2048), 16, 0, 0);
        __syncthreads();
        bf16x8 af[4], bfr[4];
#pragma unroll
        for (int m = 0; m < 4; ++m)
            af[m] = *reinterpret_cast<const bf16x8*>(&As[(wr + m * 16 + lr) * 32 + lk8]);
#pragma unroll
        for (int n = 0; n < 4; ++n)
            bfr[n] = *reinterpret_cast<const bf16x8*>(&Bs[(wc + n * 16 + lr) * 32 + lk8]);
#pragma unroll
        for (int m = 0; m < 4; ++m)
#pragma unroll
            for (int n = 0; n < 4; ++n)
                acc[m][n] = __builtin_amdgcn_mfma_f32_16x16x32_bf16(af[m], bfr[n], acc[m][n], 0, 0, 0);
        __syncthreads();
    }

    const int rb = (lane >> 4) << 2;
    if (OUTF32) {
        float* C = reinterpret_cast<float*>(Cp);
#pragma unroll
        for (int m = 0; m < 4; ++m)
#pragma unroll
            for (int n = 0; n < 4; ++n) {
                const int col = bn * 128 + wc + n * 16 + lr;
                const float bv = bias[col];
#pragma unroll
                for (int r = 0; r < 4; ++r) {
                    const int row = bm * 128 + wr + m * 16 + rb + r;
                    C[(size_t)row * N + col] = acc[m][n][r] + bv;
                }
            }
    } else {
        unsigned short* C = reinterpret_cast<unsigned short*>(Cp);
#pragma unroll
        for (int m = 0; m < 4; ++m)
#pragma unroll
            for (int n = 0; n < 4; ++n) {
                const int col = bn * 128 + wc + n * 16 + lr;
#pragma unroll
                for (int r = 0; r < 4; ++r) {
                    const int row = bm * 128 + wr + m * 16 + rb + r;
                    C[(size_t)row * N + col] = f2b(acc[m][n][r]);
                }
            }
    }
}

// ------------- fused flash attention with key-length masking (v3) -------------
// grid 2048, block 256 = 4 waves, 16 q-rows/wave.
// v3 change: LOAD-BALANCED block swizzle. Round-3's swizzle aliased batch<->XCD
// (work per block ~ L_b, random per batch -> one XCD got all the long blocks,
// 1.9x regression). New decode keeps b varying in LOW bits adjacent to the
// xcd field so per-XCD work = 2*sum_b(L_b) under round-robin dispatch AND
// balanced under chunked dispatch; h-field in bits[2:0] gives each XCD just
// 16 KV panels (4MB = one L2) under round-robin.
__global__ __launch_bounds__(256, 2)
void attn_fused(const unsigned short* __restrict__ Q,   // [8192][1024]
                const unsigned short* __restrict__ KV,  // [8192][2048] (k | v)
                const int* __restrict__ lengths,
                unsigned short* __restrict__ O) {       // [8192][1024]
    __shared__ unsigned short Vt[64 * 72];      // [d][key], stride 72
    __shared__ unsigned short Pl[4][16 * 72];   // per-wave [q][key], stride 72

    const int tid  = threadIdx.x;
    const int wave = tid >> 6;
    const int lane = tid & 63;
    // bid bits: [2:0] -> h low (xcd field), [5:3] -> b, [6] -> h high, [10:7] -> qt
    const int bid = blockIdx.x;
    const int h  = ((bid >> 6) & 1) * 8 + (bid & 7);
    const int b  = (bid >> 3) & 7;
    const int qt = bid >> 7;
    const int L  = lengths[b];

    const int lr  = lane & 15;
    const int g   = lane >> 4;
    const int lk8 = g << 3;     // 0,8,16,24
    const int rb  = g << 2;     // 0,4,8,12

    const size_t kvbase = (size_t)(b * 1024) * 2048 + h * 64;

    // Q fragments (A-operand: row=lane&15, k=(lane>>4)*8+j within 32-slice)
    const size_t qrow = (size_t)(b * 1024 + qt * 64 + wave * 16 + lr);
    bf16x8 qf[2];
    qf[0] = *reinterpret_cast<const bf16x8*>(&Q[qrow * 1024 + h * 64 + lk8]);
    qf[1] = *reinterpret_cast<const bf16x8*>(&Q[qrow * 1024 + h * 64 + 32 + lk8]);

    f32x4 oacc[4];
#pragma unroll
    for (int nd = 0; nd < 4; ++nd) oacc[nd] = (f32x4){0.f, 0.f, 0.f, 0.f};
    float mrun[4] = {-3.0e38f, -3.0e38f, -3.0e38f, -3.0e38f};
    float lrun[4] = {0.f, 0.f, 0.f, 0.f};

    const int ntiles = (L + 63) >> 6;
    for (int t = 0; t < ntiles; ++t) {
        const int j0 = t * 64;
        __syncthreads();   // all PV reads of Vt[t-1] done before overwrite

        // ---- V stage: global -> reg (issued early, hides under QK^T) ----
        bf16x8 vv[2];
#pragma unroll
        for (int rep = 0; rep < 2; ++rep) {
            const int dseg = ((rep * 4 + wave) & 7) << 3;
            vv[rep] = *reinterpret_cast<const bf16x8*>(
                &KV[kvbase + (size_t)(j0 + lane) * 2048 + 1024 + dseg]);
        }

        // ---- S = Q K^T, K fragments direct from global ----
        f32x4 sacc[4];
#pragma unroll
        for (int n = 0; n < 4; ++n) sacc[n] = (f32x4){0.f, 0.f, 0.f, 0.f};
#pragma unroll
        for (int n = 0; n < 4; ++n) {
            const unsigned short* kp = &KV[kvbase + (size_t)(j0 + n * 16 + lr) * 2048 + lk8];
            bf16x8 kf0 = *reinterpret_cast<const bf16x8*>(kp);
            bf16x8 kf1 = *reinterpret_cast<const bf16x8*>(kp + 32);
            sacc[n] = __builtin_amdgcn_mfma_f32_16x16x32_bf16(qf[0], kf0, sacc[n], 0, 0, 0);
            sacc[n] = __builtin_amdgcn_mfma_f32_16x16x32_bf16(qf[1], kf1, sacc[n], 0, 0, 0);
        }

        // ---- V transpose writes: per-instr addr = const + lane (conflict-free) ----
#pragma unroll
        for (int rep = 0; rep < 2; ++rep) {
            const int dseg = ((rep * 4 + wave) & 7) << 3;
#pragma unroll
            for (int j = 0; j < 8; ++j)
                Vt[(dseg + j) * 72 + lane] = (unsigned short)vv[rep][j];
        }

        // ---- scale + mask ----
        float sv[4][4];
#pragma unroll
        for (int n = 0; n < 4; ++n)
#pragma unroll
            for (int r = 0; r < 4; ++r) {
                const int key = j0 + n * 16 + lr;
                sv[n][r] = (key < L) ? sacc[n][r] * 0.125f : -3.0e38f;
            }

        // ---- online softmax (row r of 16-lane group) ----
        float alpha[4], psum[4];
#pragma unroll
        for (int r = 0; r < 4; ++r) {
            float tm = fmaxf(fmaxf(sv[0][r], sv[1][r]), fmaxf(sv[2][r], sv[3][r]));
#pragma unroll
            for (int off = 1; off < 16; off <<= 1)
                tm = fmaxf(tm, __shfl_xor(tm, off));
            const float mn = fmaxf(mrun[r], tm);
            alpha[r] = __expf(mrun[r] - mn);
            mrun[r] = mn;
            psum[r] = 0.f;
        }
        float pv[4][4];
#pragma unroll
        for (int n = 0; n < 4; ++n)
#pragma unroll
            for (int r = 0; r < 4; ++r) {
                const float p = __expf(sv[n][r] - mrun[r]);
                pv[n][r] = p;
                psum[r] += p;
            }
#pragma unroll
        for (int r = 0; r < 4; ++r) {
#pragma unroll
            for (int off = 1; off < 16; off <<= 1)
                psum[r] += __shfl_xor(psum[r], off);
            lrun[r] = lrun[r] * alpha[r] + psum[r];
        }
#pragma unroll
        for (int nd = 0; nd < 4; ++nd)
#pragma unroll
            for (int r = 0; r < 4; ++r)
                oacc[nd][r] *= alpha[r];

        // ---- P -> per-wave LDS (no barrier needed: same-wave dep) ----
#pragma unroll
        for (int n = 0; n < 4; ++n)
#pragma unroll
            for (int r = 0; r < 4; ++r)
                Pl[wave][(rb + r) * 72 + n * 16 + lr] = f2b(pv[n][r]);

        __syncthreads();   // Vt fully staged by all waves before PV

        // ---- O += P V ----
        bf16x8 pf0 = *reinterpret_cast<const bf16x8*>(&Pl[wave][lr * 72 + lk8]);
        bf16x8 pf1 = *reinterpret_cast<const bf16x8*>(&Pl[wave][lr * 72 + 32 + lk8]);
#pragma unroll
        for (int nd = 0; nd < 4; ++nd) {
            bf16x8 vf0 = *reinterpret_cast<const bf16x8*>(&Vt[(nd * 16 + lr) * 72 + lk8]);
            bf16x8 vf1 = *reinterpret_cast<const bf16x8*>(&Vt[(nd * 16 + lr) * 72 + 32 + lk8]);
            oacc[nd] = __builtin_amdgcn_mfma_f32_16x16x32_bf16(pf0, vf0, oacc[nd], 0, 0, 0);
            oacc[nd] = __builtin_amdgcn_mfma_f32_16x16x32_bf16(pf1, vf1, oacc[nd], 0, 0, 0);
        }
    }

    // ---- normalize + write ----
    const size_t orow = (size_t)(b * 1024 + qt * 64 + wave * 16);
#pragma unroll
    for (int r = 0; r < 4; ++r) {
        const float inv = 1.0f / lrun[r];
#pragma unroll
        for (int nd = 0; nd < 4; ++nd)
            O[(orow + rb + r) * 1024 + h * 64 + nd * 16 + lr] = f2b(oacc[nd][r] * inv);
    }
}

extern "C" void kernel_launch(void* const* d_in, const int* in_sizes, int n_in,
                              void* d_out, int out_size, void* d_ws, size_t ws_size,
                              hipStream_t stream) {
    const float* x    = (const float*)d_in[0];
    const float* ctx  = (const float*)d_in[1];
    const int*   len  = (const int*)d_in[2];
    const float* Wq   = (const float*)d_in[3];
    const float* Wkv  = (const float*)d_in[4];
    const float* Wout = (const float*)d_in[5];
    const float* bout = (const float*)d_in[6];
    float* out = (float*)d_out;

    char* w = (char*)d_ws;
    unsigned short* xb   = (unsigned short*)w; w += (size_t)8192 * 1024 * 2;
    unsigned short* cb   = (unsigned short*)w; w += (size_t)8192 * 1024 * 2;
    unsigned short* qb   = (unsigned short*)w; w += (size_t)8192 * 1024 * 2;
    unsigned short* kvb  = (unsigned short*)w; w += (size_t)8192 * 2048 * 2;
    unsigned short* aob  = (unsigned short*)w; w += (size_t)8192 * 1024 * 2;
    unsigned short* wqt  = (unsigned short*)w; w += (size_t)1024 * 1024 * 2;
    unsigned short* wkvt = (unsigned short*)w; w += (size_t)2048 * 1024 * 2;
    unsigned short* wot  = (unsigned short*)w; w += (size_t)1024 * 1024 * 2;

    cast_f32_to_bf16<<<2048, 256, 0, stream>>>(x,   xb, 8192 * 1024);
    cast_f32_to_bf16<<<2048, 256, 0, stream>>>(ctx, cb, 8192 * 1024);
    dim3 tb(32, 8);
    transpose_cast<<<dim3(32, 32), tb, 0, stream>>>(Wq,   wqt,  1024, 1024);
    transpose_cast<<<dim3(64, 32), tb, 0, stream>>>(Wkv,  wkvt, 1024, 2048);
    transpose_cast<<<dim3(32, 32), tb, 0, stream>>>(Wout, wot,  1024, 1024);

    gemm_bt<0><<<512,  256, 0, stream>>>(xb, wqt,  (void*)qb,  nullptr, 8192, 1024, 1024);
    gemm_bt<0><<<1024, 256, 0, stream>>>(cb, wkvt, (void*)kvb, nullptr, 8192, 2048, 1024);
    attn_fused<<<2048, 256, 0, stream>>>(qb, kvb, len, aob);
    gemm_bt<1><<<512,  256, 0, stream>>>(aob, wot, (void*)out, bout, 8192, 1024, 1024);
}

// Round 5
// 349.030 us; speedup vs baseline: 1.1068x; 1.0653x over previous
//
#include <hip/hip_runtime.h>
#include <hip/hip_bf16.h>
#include <math.h>

typedef __attribute__((ext_vector_type(4))) float f32x4;
typedef __attribute__((ext_vector_type(8))) short bf16x8;

#define DEVI __device__ __forceinline__
#define GLBP(p) ((const __attribute__((address_space(1))) void*)(p))
#define LDSP(p) ((__attribute__((address_space(3))) void*)(p))

DEVI unsigned short f2b(float x) {
    __hip_bfloat16 b = __float2bfloat16(x);
    return *reinterpret_cast<unsigned short*>(&b);
}

// ---------------- cast f32 -> bf16, vectorized ----------------
__global__ void cast_f32_to_bf16(const float* __restrict__ in,
                                 unsigned short* __restrict__ out, int n) {
    int stride = gridDim.x * blockDim.x;
    for (int i = blockIdx.x * blockDim.x + threadIdx.x; i * 4 < n; i += stride) {
        float4 v = reinterpret_cast<const float4*>(in)[i];
        ushort4 o;
        o.x = f2b(v.x); o.y = f2b(v.y); o.z = f2b(v.z); o.w = f2b(v.w);
        reinterpret_cast<ushort4*>(out)[i] = o;
    }
}

// ------------- transpose+cast: f32 [R][C] -> bf16 [C][R] -------------
__global__ void transpose_cast(const float* __restrict__ in,
                               unsigned short* __restrict__ out, int R, int C) {
    __shared__ float t[32][33];
    int bc = blockIdx.x * 32, br = blockIdx.y * 32;
    int x = threadIdx.x, y = threadIdx.y;   // block (32,8)
#pragma unroll
    for (int j = 0; j < 32; j += 8)
        t[y + j][x] = in[(size_t)(br + y + j) * C + bc + x];
    __syncthreads();
#pragma unroll
    for (int j = 0; j < 32; j += 8)
        out[(size_t)(bc + y + j) * R + br + x] = f2b(t[x][y + j]);
}

// ------------- GEMM: C[M,N] = A[M,K] * B[N,K]^T (bf16 in, bf16/f32 out) -------------
template<int OUTF32>
__global__ __launch_bounds__(256, 2)
void gemm_bt(const unsigned short* __restrict__ A,
             const unsigned short* __restrict__ B,
             void* __restrict__ Cp, const float* __restrict__ bias,
             int M, int N, int K) {
    __shared__ unsigned short As[128 * 32];
    __shared__ unsigned short Bs[128 * 32];
    const int tid  = threadIdx.x;
    const int wave = tid >> 6;
    const int lane = tid & 63;
    const int nbn  = N >> 7;
    const int bm   = blockIdx.x / nbn;
    const int bn   = blockIdx.x - bm * nbn;

    const int lr  = lane & 15;
    const int lk8 = (lane >> 4) << 3;
    const int wr  = (wave >> 1) * 64;
    const int wc  = (wave & 1) * 64;

    const unsigned short* ag = A + (size_t)(bm * 128 + (tid >> 2)) * K + ((tid & 3) << 3);
    const unsigned short* bg = B + (size_t)(bn * 128 + (tid >> 2)) * K + ((tid & 3) << 3);
    unsigned short* asd = As + wave * 512;   // wave-uniform LDS dest
    unsigned short* bsd = Bs + wave * 512;

    f32x4 acc[4][4];
#pragma unroll
    for (int m = 0; m < 4; ++m)
#pragma unroll
        for (int n = 0; n < 4; ++n)
            acc[m][n] = (f32x4){0.f, 0.f, 0.f, 0.f};

    for (int k0 = 0; k0 < K; k0 += 32) {
        __builtin_amdgcn_global_load_lds(GLBP(ag + k0),                    LDSP(asd),        16, 0, 0);
        __builtin_amdgcn_global_load_lds(GLBP(ag + (size_t)64 * K + k0),   LDSP(asd + 2048), 16, 0, 0);
        __builtin_amdgcn_global_load_lds(GLBP(bg + k0),                    LDSP(bsd),        16, 0, 0);
        __builtin_amdgcn_global_load_lds(GLBP(bg + (size_t)64 * K + k0),   LDSP(bsd + 2048), 16, 0, 0);
        __syncthreads();
        bf16x8 af[4], bfr[4];
#pragma unroll
        for (int m = 0; m < 4; ++m)
            af[m] = *reinterpret_cast<const bf16x8*>(&As[(wr + m * 16 + lr) * 32 + lk8]);
#pragma unroll
        for (int n = 0; n < 4; ++n)
            bfr[n] = *reinterpret_cast<const bf16x8*>(&Bs[(wc + n * 16 + lr) * 32 + lk8]);
#pragma unroll
        for (int m = 0; m < 4; ++m)
#pragma unroll
            for (int n = 0; n < 4; ++n)
                acc[m][n] = __builtin_amdgcn_mfma_f32_16x16x32_bf16(af[m], bfr[n], acc[m][n], 0, 0, 0);
        __syncthreads();
    }

    const int rb = (lane >> 4) << 2;
    if (OUTF32) {
        float* C = reinterpret_cast<float*>(Cp);
#pragma unroll
        for (int m = 0; m < 4; ++m)
#pragma unroll
            for (int n = 0; n < 4; ++n) {
                const int col = bn * 128 + wc + n * 16 + lr;
                const float bv = bias[col];
#pragma unroll
                for (int r = 0; r < 4; ++r) {
                    const int row = bm * 128 + wr + m * 16 + rb + r;
                    C[(size_t)row * N + col] = acc[m][n][r] + bv;
                }
            }
    } else {
        unsigned short* C = reinterpret_cast<unsigned short*>(Cp);
#pragma unroll
        for (int m = 0; m < 4; ++m)
#pragma unroll
            for (int n = 0; n < 4; ++n) {
                const int col = bn * 128 + wc + n * 16 + lr;
#pragma unroll
                for (int r = 0; r < 4; ++r) {
                    const int row = bm * 128 + wr + m * 16 + rb + r;
                    C[(size_t)row * N + col] = f2b(acc[m][n][r]);
                }
            }
    }
}

// ------------- fused flash attention with key-length masking (v4) -------------
// Round-2 skeleton (coalesced reg-staged K/V, LDS operands) +:
//  - Vt ROTATION layout: element (key,d) at Vt[d*72 + ((key + (d&56)) & 63)].
//    Per store instr, (key+dseg) is a lane-bijection -> col>>1 covers all 32
//    banks 2x -> 2-way = free (was 16-way at plain stride-72). Reads stay
//    contiguous + 16B-aligned (rotation is by a multiple of 8 keys).
//  - T14 prefetch: issue tile t+1's K/V global loads right after writing
//    tile t's regs to LDS; compute phase hides the latency.
//  - launch_bounds(256,4): 4 blocks/CU (was 2) for latency hiding.
__global__ __launch_bounds__(256, 4)
void attn_fused(const unsigned short* __restrict__ Q,   // [8192][1024]
                const unsigned short* __restrict__ KV,  // [8192][2048] (k | v)
                const int* __restrict__ lengths,
                unsigned short* __restrict__ O) {       // [8192][1024]
    __shared__ unsigned short Kl[64 * 72];      // [key][d], stride 72
    __shared__ unsigned short Vt[64 * 72];      // [d][rot(key)], stride 72
    __shared__ unsigned short Pl[4][16 * 72];   // per-wave [q][key], stride 72

    const int tid  = threadIdx.x;
    const int wave = tid >> 6;
    const int lane = tid & 63;
    // balanced decode: h-low in bits[2:0] (xcd field), b in [5:3], h-high [6], qt [10:7]
    const int bid = blockIdx.x;
    const int h  = ((bid >> 6) & 1) * 8 + (bid & 7);
    const int b  = (bid >> 3) & 7;
    const int qt = bid >> 7;
    const int L  = lengths[b];

    const int lr  = lane & 15;
    const int g   = lane >> 4;
    const int lk8 = g << 3;     // 0,8,16,24
    const int rb  = g << 2;     // 0,4,8,12

    // staging assignment (coalesced): key0 = tid>>3 (+32 for rep 1), dseg = (tid&7)*8
    const int skey = tid >> 3;          // 0..31
    const int sds  = (tid & 7) << 3;    // 0..56
    const int vcol0 = (skey + sds) & 63;        // Vt rotated col, rep 0
    const int vcol1 = (skey + 32 + sds) & 63;   // rep 1

    const size_t kvbase = (size_t)(b * 1024) * 2048 + h * 64;

    // Q fragments (A-operand: row=lane&15, k=(lane>>4)*8+j within 32-slice)
    const size_t qrow = (size_t)(b * 1024 + qt * 64 + wave * 16 + lr);
    bf16x8 qf[2];
    qf[0] = *reinterpret_cast<const bf16x8*>(&Q[qrow * 1024 + h * 64 + lk8]);
    qf[1] = *reinterpret_cast<const bf16x8*>(&Q[qrow * 1024 + h * 64 + 32 + lk8]);

    f32x4 oacc[4];
#pragma unroll
    for (int nd = 0; nd < 4; ++nd) oacc[nd] = (f32x4){0.f, 0.f, 0.f, 0.f};
    float mrun[4] = {-3.0e38f, -3.0e38f, -3.0e38f, -3.0e38f};
    float lrun[4] = {0.f, 0.f, 0.f, 0.f};

    const int ntiles = (L + 63) >> 6;

    // ---- prologue: load tile 0 K/V into regs (coalesced) ----
    bf16x8 kreg[2], vreg[2];
    {
        const size_t r0 = kvbase + (size_t)(skey)      * 2048 + sds;
        const size_t r1 = kvbase + (size_t)(skey + 32) * 2048 + sds;
        kreg[0] = *reinterpret_cast<const bf16x8*>(&KV[r0]);
        kreg[1] = *reinterpret_cast<const bf16x8*>(&KV[r1]);
        vreg[0] = *reinterpret_cast<const bf16x8*>(&KV[r0 + 1024]);
        vreg[1] = *reinterpret_cast<const bf16x8*>(&KV[r1 + 1024]);
    }

    for (int t = 0; t < ntiles; ++t) {
        __syncthreads();   // PV(t-1) readers done before overwrite

        // ---- write staged regs (tile t) to LDS ----
        *reinterpret_cast<bf16x8*>(&Kl[skey * 72 + sds])        = kreg[0];
        *reinterpret_cast<bf16x8*>(&Kl[(skey + 32) * 72 + sds]) = kreg[1];
#pragma unroll
        for (int j = 0; j < 8; ++j)
            Vt[(sds + j) * 72 + vcol0] = (unsigned short)vreg[0][j];
#pragma unroll
        for (int j = 0; j < 8; ++j)
            Vt[(sds + j) * 72 + vcol1] = (unsigned short)vreg[1][j];

        // ---- issue tile t+1 loads (latency hidden under compute(t)) ----
        {
            const int j0n = (t + 1) * 64;
            int r0i = j0n + skey;        r0i = r0i > 1023 ? 1023 : r0i;
            int r1i = j0n + skey + 32;   r1i = r1i > 1023 ? 1023 : r1i;
            const size_t r0 = kvbase + (size_t)r0i * 2048 + sds;
            const size_t r1 = kvbase + (size_t)r1i * 2048 + sds;
            kreg[0] = *reinterpret_cast<const bf16x8*>(&KV[r0]);
            kreg[1] = *reinterpret_cast<const bf16x8*>(&KV[r1]);
            vreg[0] = *reinterpret_cast<const bf16x8*>(&KV[r0 + 1024]);
            vreg[1] = *reinterpret_cast<const bf16x8*>(&KV[r1 + 1024]);
        }

        __syncthreads();   // tile t fully staged

        const int j0 = t * 64;

        // ---- S = Q K^T from Kl ----
        f32x4 sacc[4];
#pragma unroll
        for (int n = 0; n < 4; ++n) sacc[n] = (f32x4){0.f, 0.f, 0.f, 0.f};
#pragma unroll
        for (int n = 0; n < 4; ++n) {
            bf16x8 kf0 = *reinterpret_cast<const bf16x8*>(&Kl[(n * 16 + lr) * 72 + lk8]);
            bf16x8 kf1 = *reinterpret_cast<const bf16x8*>(&Kl[(n * 16 + lr) * 72 + 32 + lk8]);
            sacc[n] = __builtin_amdgcn_mfma_f32_16x16x32_bf16(qf[0], kf0, sacc[n], 0, 0, 0);
            sacc[n] = __builtin_amdgcn_mfma_f32_16x16x32_bf16(qf[1], kf1, sacc[n], 0, 0, 0);
        }

        // ---- scale + mask ----
        float sv[4][4];
#pragma unroll
        for (int n = 0; n < 4; ++n)
#pragma unroll
            for (int r = 0; r < 4; ++r) {
                const int key = j0 + n * 16 + lr;
                sv[n][r] = (key < L) ? sacc[n][r] * 0.125f : -3.0e38f;
            }

        // ---- online softmax (row r of 16-lane group) ----
        float alpha[4], psum[4];
#pragma unroll
        for (int r = 0; r < 4; ++r) {
            float tm = fmaxf(fmaxf(sv[0][r], sv[1][r]), fmaxf(sv[2][r], sv[3][r]));
#pragma unroll
            for (int off = 1; off < 16; off <<= 1)
                tm = fmaxf(tm, __shfl_xor(tm, off));
            const float mn = fmaxf(mrun[r], tm);
            alpha[r] = __expf(mrun[r] - mn);
            mrun[r] = mn;
            psum[r] = 0.f;
        }
        float pv[4][4];
#pragma unroll
        for (int n = 0; n < 4; ++n)
#pragma unroll
            for (int r = 0; r < 4; ++r) {
                const float p = __expf(sv[n][r] - mrun[r]);
                pv[n][r] = p;
                psum[r] += p;
            }
#pragma unroll
        for (int r = 0; r < 4; ++r) {
#pragma unroll
            for (int off = 1; off < 16; off <<= 1)
                psum[r] += __shfl_xor(psum[r], off);
            lrun[r] = lrun[r] * alpha[r] + psum[r];
        }
#pragma unroll
        for (int nd = 0; nd < 4; ++nd)
#pragma unroll
            for (int r = 0; r < 4; ++r)
                oacc[nd][r] *= alpha[r];

        // ---- P -> per-wave LDS (same-wave dep, no barrier) ----
#pragma unroll
        for (int n = 0; n < 4; ++n)
#pragma unroll
            for (int r = 0; r < 4; ++r)
                Pl[wave][(rb + r) * 72 + n * 16 + lr] = f2b(pv[n][r]);

        // ---- O += P V (Vt read with rotation) ----
        bf16x8 pf0 = *reinterpret_cast<const bf16x8*>(&Pl[wave][lr * 72 + lk8]);
        bf16x8 pf1 = *reinterpret_cast<const bf16x8*>(&Pl[wave][lr * 72 + 32 + lk8]);
#pragma unroll
        for (int nd = 0; nd < 4; ++nd) {
            const int d = nd * 16 + lr;
            const int c0 = (lk8 + (d & 56)) & 63;
            const int c1 = ((32 + lk8) + (d & 56)) & 63;
            bf16x8 vf0 = *reinterpret_cast<const bf16x8*>(&Vt[d * 72 + c0]);
            bf16x8 vf1 = *reinterpret_cast<const bf16x8*>(&Vt[d * 72 + c1]);
            oacc[nd] = __builtin_amdgcn_mfma_f32_16x16x32_bf16(pf0, vf0, oacc[nd], 0, 0, 0);
            oacc[nd] = __builtin_amdgcn_mfma_f32_16x16x32_bf16(pf1, vf1, oacc[nd], 0, 0, 0);
        }
    }

    // ---- normalize + write ----
    const size_t orow = (size_t)(b * 1024 + qt * 64 + wave * 16);
#pragma unroll
    for (int r = 0; r < 4; ++r) {
        const float inv = 1.0f / lrun[r];
#pragma unroll
        for (int nd = 0; nd < 4; ++nd)
            O[(orow + rb + r) * 1024 + h * 64 + nd * 16 + lr] = f2b(oacc[nd][r] * inv);
    }
}

extern "C" void kernel_launch(void* const* d_in, const int* in_sizes, int n_in,
                              void* d_out, int out_size, void* d_ws, size_t ws_size,
                              hipStream_t stream) {
    const float* x    = (const float*)d_in[0];
    const float* ctx  = (const float*)d_in[1];
    const int*   len  = (const int*)d_in[2];
    const float* Wq   = (const float*)d_in[3];
    const float* Wkv  = (const float*)d_in[4];
    const float* Wout = (const float*)d_in[5];
    const float* bout = (const float*)d_in[6];
    float* out = (float*)d_out;

    char* w = (char*)d_ws;
    unsigned short* xb   = (unsigned short*)w; w += (size_t)8192 * 1024 * 2;
    unsigned short* cb   = (unsigned short*)w; w += (size_t)8192 * 1024 * 2;
    unsigned short* qb   = (unsigned short*)w; w += (size_t)8192 * 1024 * 2;
    unsigned short* kvb  = (unsigned short*)w; w += (size_t)8192 * 2048 * 2;
    unsigned short* aob  = (unsigned short*)w; w += (size_t)8192 * 1024 * 2;
    unsigned short* wqt  = (unsigned short*)w; w += (size_t)1024 * 1024 * 2;
    unsigned short* wkvt = (unsigned short*)w; w += (size_t)2048 * 1024 * 2;
    unsigned short* wot  = (unsigned short*)w; w += (size_t)1024 * 1024 * 2;

    cast_f32_to_bf16<<<2048, 256, 0, stream>>>(x,   xb, 8192 * 1024);
    cast_f32_to_bf16<<<2048, 256, 0, stream>>>(ctx, cb, 8192 * 1024);
    dim3 tb(32, 8);
    transpose_cast<<<dim3(32, 32), tb, 0, stream>>>(Wq,   wqt,  1024, 1024);
    transpose_cast<<<dim3(64, 32), tb, 0, stream>>>(Wkv,  wkvt, 1024, 2048);
    transpose_cast<<<dim3(32, 32), tb, 0, stream>>>(Wout, wot,  1024, 1024);

    gemm_bt<0><<<512,  256, 0, stream>>>(xb, wqt,  (void*)qb,  nullptr, 8192, 1024, 1024);
    gemm_bt<0><<<1024, 256, 0, stream>>>(cb, wkvt, (void*)kvb, nullptr, 8192, 2048, 1024);
    attn_fused<<<2048, 256, 0, stream>>>(qb, kvb, len, aob);
    gemm_bt<1><<<512,  256, 0, stream>>>(aob, wot, (void*)out, bout, 8192, 1024, 1024);
}

// Round 7
// 336.783 us; speedup vs baseline: 1.1471x; 1.0364x over previous
//
#include <hip/hip_runtime.h>
#include <hip/hip_bf16.h>
#include <math.h>

typedef __attribute__((ext_vector_type(4))) float f32x4;
typedef __attribute__((ext_vector_type(8))) short bf16x8;

#define DEVI __device__ __forceinline__
#define GLBP(p) ((const __attribute__((address_space(1))) void*)(p))
#define LDSP(p) ((__attribute__((address_space(3))) void*)(p))

DEVI unsigned short f2b(float x) {
    __hip_bfloat16 b = __float2bfloat16(x);
    return *reinterpret_cast<unsigned short*>(&b);
}

// ---------------- cast f32 -> bf16, vectorized ----------------
__global__ void cast_f32_to_bf16(const float* __restrict__ in,
                                 unsigned short* __restrict__ out, int n) {
    int stride = gridDim.x * blockDim.x;
    for (int i = blockIdx.x * blockDim.x + threadIdx.x; i * 4 < n; i += stride) {
        float4 v = reinterpret_cast<const float4*>(in)[i];
        ushort4 o;
        o.x = f2b(v.x); o.y = f2b(v.y); o.z = f2b(v.z); o.w = f2b(v.w);
        reinterpret_cast<ushort4*>(out)[i] = o;
    }
}

// ------------- transpose+cast: f32 [R][C] -> bf16 [C][R] -------------
__global__ void transpose_cast(const float* __restrict__ in,
                               unsigned short* __restrict__ out, int R, int C) {
    __shared__ float t[32][33];
    int bc = blockIdx.x * 32, br = blockIdx.y * 32;
    int x = threadIdx.x, y = threadIdx.y;   // block (32,8)
#pragma unroll
    for (int j = 0; j < 32; j += 8)
        t[y + j][x] = in[(size_t)(br + y + j) * C + bc + x];
    __syncthreads();
#pragma unroll
    for (int j = 0; j < 32; j += 8)
        out[(size_t)(bc + y + j) * R + br + x] = f2b(t[x][y + j]);
}

// ------------- GEMM: C[M,N] = A[M,K] * B[N,K]^T (bf16 in, bf16/f32 out) -------------
template<int OUTF32>
__global__ __launch_bounds__(256, 2)
void gemm_bt(const unsigned short* __restrict__ A,
             const unsigned short* __restrict__ B,
             void* __restrict__ Cp, const float* __restrict__ bias,
             int M, int N, int K) {
    __shared__ unsigned short As[128 * 32];
    __shared__ unsigned short Bs[128 * 32];
    const int tid  = threadIdx.x;
    const int wave = tid >> 6;
    const int lane = tid & 63;
    const int nbn  = N >> 7;
    const int bm   = blockIdx.x / nbn;
    const int bn   = blockIdx.x - bm * nbn;

    const int lr  = lane & 15;
    const int lk8 = (lane >> 4) << 3;
    const int wr  = (wave >> 1) * 64;
    const int wc  = (wave & 1) * 64;

    const unsigned short* ag = A + (size_t)(bm * 128 + (tid >> 2)) * K + ((tid & 3) << 3);
    const unsigned short* bg = B + (size_t)(bn * 128 + (tid >> 2)) * K + ((tid & 3) << 3);
    unsigned short* asd = As + wave * 512;   // wave-uniform LDS dest
    unsigned short* bsd = Bs + wave * 512;

    f32x4 acc[4][4];
#pragma unroll
    for (int m = 0; m < 4; ++m)
#pragma unroll
        for (int n = 0; n < 4; ++n)
            acc[m][n] = (f32x4){0.f, 0.f, 0.f, 0.f};

    for (int k0 = 0; k0 < K; k0 += 32) {
        __builtin_amdgcn_global_load_lds(GLBP(ag + k0),                    LDSP(asd),        16, 0, 0);
        __builtin_amdgcn_global_load_lds(GLBP(ag + (size_t)64 * K + k0),   LDSP(asd + 2048), 16, 0, 0);
        __builtin_amdgcn_global_load_lds(GLBP(bg + k0),                    LDSP(bsd),        16, 0, 0);
        __builtin_amdgcn_global_load_lds(GLBP(bg + (size_t)64 * K + k0),   LDSP(bsd + 2048), 16, 0, 0);
        __syncthreads();
        bf16x8 af[4], bfr[4];
#pragma unroll
        for (int m = 0; m < 4; ++m)
            af[m] = *reinterpret_cast<const bf16x8*>(&As[(wr + m * 16 + lr) * 32 + lk8]);
#pragma unroll
        for (int n = 0; n < 4; ++n)
            bfr[n] = *reinterpret_cast<const bf16x8*>(&Bs[(wc + n * 16 + lr) * 32 + lk8]);
#pragma unroll
        for (int m = 0; m < 4; ++m)
#pragma unroll
            for (int n = 0; n < 4; ++n)
                acc[m][n] = __builtin_amdgcn_mfma_f32_16x16x32_bf16(af[m], bfr[n], acc[m][n], 0, 0, 0);
        __syncthreads();
    }

    const int rb = (lane >> 4) << 2;
    if (OUTF32) {
        float* C = reinterpret_cast<float*>(Cp);
#pragma unroll
        for (int m = 0; m < 4; ++m)
#pragma unroll
            for (int n = 0; n < 4; ++n) {
                const int col = bn * 128 + wc + n * 16 + lr;
                const float bv = bias[col];
#pragma unroll
                for (int r = 0; r < 4; ++r) {
                    const int row = bm * 128 + wr + m * 16 + rb + r;
                    C[(size_t)row * N + col] = acc[m][n][r] + bv;
                }
            }
    } else {
        unsigned short* C = reinterpret_cast<unsigned short*>(Cp);
#pragma unroll
        for (int m = 0; m < 4; ++m)
#pragma unroll
            for (int n = 0; n < 4; ++n) {
                const int col = bn * 128 + wc + n * 16 + lr;
#pragma unroll
                for (int r = 0; r < 4; ++r) {
                    const int row = bm * 128 + wr + m * 16 + rb + r;
                    C[(size_t)row * N + col] = f2b(acc[m][n][r]);
                }
            }
    }
}

// ------------- fused flash attention with key-length masking (v5) -------------
// v5 change: PERSISTENT blocks + dynamic work queue. Diagnosis from rounds 3-5:
// grid of 2048 one-shot blocks with 16x per-block work skew (L in 1..1024)
// left a sparse long-L tail running at 1-2 blocks/CU (occ pinned ~16%).
// Now 1280 persistent blocks (5/CU: LDS 5*27.6KB=138<=160KB) pull the 2048
// (b,h,qt) items from an atomicAdd counter -> machine stays full; tail = 1 item.
// Inner loop identical to round 5 (rotation Vt layout + reg prefetch).
__global__ __launch_bounds__(256, 5)
void attn_fused(const unsigned short* __restrict__ Q,   // [8192][1024]
                const unsigned short* __restrict__ KV,  // [8192][2048] (k | v)
                const int* __restrict__ lengths,
                unsigned short* __restrict__ O,         // [8192][1024]
                unsigned int* __restrict__ ctr) {
    __shared__ unsigned short Kl[64 * 72];      // [key][d], stride 72
    __shared__ unsigned short Vt[64 * 72];      // [d][rot(key)], stride 72
    __shared__ unsigned short Pl[4][16 * 72];   // per-wave [q][key], stride 72
    __shared__ int s_item;

    const int tid  = threadIdx.x;
    const int wave = tid >> 6;
    const int lane = tid & 63;

    const int lr  = lane & 15;
    const int g   = lane >> 4;
    const int lk8 = g << 3;     // 0,8,16,24
    const int rb  = g << 2;     // 0,4,8,12

    // staging assignment (coalesced): key0 = tid>>3 (+32 rep1), dseg=(tid&7)*8
    const int skey = tid >> 3;          // 0..31
    const int sds  = (tid & 7) << 3;    // 0..56
    const int vcol0 = (skey + sds) & 63;        // Vt rotated col, rep 0
    const int vcol1 = (skey + 32 + sds) & 63;   // rep 1

    while (true) {
        __syncthreads();   // prev item's s_item reads + Vt/Pl reads done
        if (tid == 0) s_item = (int)atomicAdd(ctr, 1u);
        __syncthreads();
        const int item = s_item;
        if (item >= 2048) break;

        // decode: consecutive items share (b,h) -> KV panel temporally hot
        const int qt = item & 15;
        const int bh = item >> 4;
        const int b  = bh >> 4;
        const int h  = bh & 15;
        const int L  = lengths[b];

        const size_t kvbase = (size_t)(b * 1024) * 2048 + h * 64;

        // Q fragments (A-operand: row=lane&15, k=(lane>>4)*8+j within 32-slice)
        const size_t qrow = (size_t)(b * 1024 + qt * 64 + wave * 16 + lr);
        bf16x8 qf[2];
        qf[0] = *reinterpret_cast<const bf16x8*>(&Q[qrow * 1024 + h * 64 + lk8]);
        qf[1] = *reinterpret_cast<const bf16x8*>(&Q[qrow * 1024 + h * 64 + 32 + lk8]);

        f32x4 oacc[4];
#pragma unroll
        for (int nd = 0; nd < 4; ++nd) oacc[nd] = (f32x4){0.f, 0.f, 0.f, 0.f};
        float mrun[4] = {-3.0e38f, -3.0e38f, -3.0e38f, -3.0e38f};
        float lrun[4] = {0.f, 0.f, 0.f, 0.f};

        const int ntiles = (L + 63) >> 6;

        // ---- prologue: load tile 0 K/V into regs (coalesced) ----
        bf16x8 kreg[2], vreg[2];
        {
            const size_t r0 = kvbase + (size_t)(skey)      * 2048 + sds;
            const size_t r1 = kvbase + (size_t)(skey + 32) * 2048 + sds;
            kreg[0] = *reinterpret_cast<const bf16x8*>(&KV[r0]);
            kreg[1] = *reinterpret_cast<const bf16x8*>(&KV[r1]);
            vreg[0] = *reinterpret_cast<const bf16x8*>(&KV[r0 + 1024]);
            vreg[1] = *reinterpret_cast<const bf16x8*>(&KV[r1 + 1024]);
        }

        for (int t = 0; t < ntiles; ++t) {
            __syncthreads();   // PV(t-1) readers done before overwrite

            // ---- write staged regs (tile t) to LDS ----
            *reinterpret_cast<bf16x8*>(&Kl[skey * 72 + sds])        = kreg[0];
            *reinterpret_cast<bf16x8*>(&Kl[(skey + 32) * 72 + sds]) = kreg[1];
#pragma unroll
            for (int j = 0; j < 8; ++j)
                Vt[(sds + j) * 72 + vcol0] = (unsigned short)vreg[0][j];
#pragma unroll
            for (int j = 0; j < 8; ++j)
                Vt[(sds + j) * 72 + vcol1] = (unsigned short)vreg[1][j];

            // ---- issue tile t+1 loads (latency hidden under compute(t)) ----
            {
                const int j0n = (t + 1) * 64;
                int r0i = j0n + skey;        r0i = r0i > 1023 ? 1023 : r0i;
                int r1i = j0n + skey + 32;   r1i = r1i > 1023 ? 1023 : r1i;
                const size_t r0 = kvbase + (size_t)r0i * 2048 + sds;
                const size_t r1 = kvbase + (size_t)r1i * 2048 + sds;
                kreg[0] = *reinterpret_cast<const bf16x8*>(&KV[r0]);
                kreg[1] = *reinterpret_cast<const bf16x8*>(&KV[r1]);
                vreg[0] = *reinterpret_cast<const bf16x8*>(&KV[r0 + 1024]);
                vreg[1] = *reinterpret_cast<const bf16x8*>(&KV[r1 + 1024]);
            }

            __syncthreads();   // tile t fully staged

            const int j0 = t * 64;

            // ---- S = Q K^T from Kl ----
            f32x4 sacc[4];
#pragma unroll
            for (int n = 0; n < 4; ++n) sacc[n] = (f32x4){0.f, 0.f, 0.f, 0.f};
#pragma unroll
            for (int n = 0; n < 4; ++n) {
                bf16x8 kf0 = *reinterpret_cast<const bf16x8*>(&Kl[(n * 16 + lr) * 72 + lk8]);
                bf16x8 kf1 = *reinterpret_cast<const bf16x8*>(&Kl[(n * 16 + lr) * 72 + 32 + lk8]);
                sacc[n] = __builtin_amdgcn_mfma_f32_16x16x32_bf16(qf[0], kf0, sacc[n], 0, 0, 0);
                sacc[n] = __builtin_amdgcn_mfma_f32_16x16x32_bf16(qf[1], kf1, sacc[n], 0, 0, 0);
            }

            // ---- scale + mask ----
            float sv[4][4];
#pragma unroll
            for (int n = 0; n < 4; ++n)
#pragma unroll
                for (int r = 0; r < 4; ++r) {
                    const int key = j0 + n * 16 + lr;
                    sv[n][r] = (key < L) ? sacc[n][r] * 0.125f : -3.0e38f;
                }

            // ---- online softmax (row r of 16-lane group) ----
            float alpha[4], psum[4];
#pragma unroll
            for (int r = 0; r < 4; ++r) {
                float tm = fmaxf(fmaxf(sv[0][r], sv[1][r]), fmaxf(sv[2][r], sv[3][r]));
#pragma unroll
                for (int off = 1; off < 16; off <<= 1)
                    tm = fmaxf(tm, __shfl_xor(tm, off));
                const float mn = fmaxf(mrun[r], tm);
                alpha[r] = __expf(mrun[r] - mn);
                mrun[r] = mn;
                psum[r] = 0.f;
            }
            float pv[4][4];
#pragma unroll
            for (int n = 0; n < 4; ++n)
#pragma unroll
                for (int r = 0; r < 4; ++r) {
                    const float p = __expf(sv[n][r] - mrun[r]);
                    pv[n][r] = p;
                    psum[r] += p;
                }
#pragma unroll
            for (int r = 0; r < 4; ++r) {
#pragma unroll
                for (int off = 1; off < 16; off <<= 1)
                    psum[r] += __shfl_xor(psum[r], off);
                lrun[r] = lrun[r] * alpha[r] + psum[r];
            }
#pragma unroll
            for (int nd = 0; nd < 4; ++nd)
#pragma unroll
                for (int r = 0; r < 4; ++r)
                    oacc[nd][r] *= alpha[r];

            // ---- P -> per-wave LDS (same-wave dep, no barrier) ----
#pragma unroll
            for (int n = 0; n < 4; ++n)
#pragma unroll
                for (int r = 0; r < 4; ++r)
                    Pl[wave][(rb + r) * 72 + n * 16 + lr] = f2b(pv[n][r]);

            // ---- O += P V (Vt read with rotation) ----
            bf16x8 pf0 = *reinterpret_cast<const bf16x8*>(&Pl[wave][lr * 72 + lk8]);
            bf16x8 pf1 = *reinterpret_cast<const bf16x8*>(&Pl[wave][lr * 72 + 32 + lk8]);
#pragma unroll
            for (int nd = 0; nd < 4; ++nd) {
                const int d = nd * 16 + lr;
                const int c0 = (lk8 + (d & 56)) & 63;
                const int c1 = ((32 + lk8) + (d & 56)) & 63;
                bf16x8 vf0 = *reinterpret_cast<const bf16x8*>(&Vt[d * 72 + c0]);
                bf16x8 vf1 = *reinterpret_cast<const bf16x8*>(&Vt[d * 72 + c1]);
                oacc[nd] = __builtin_amdgcn_mfma_f32_16x16x32_bf16(pf0, vf0, oacc[nd], 0, 0, 0);
                oacc[nd] = __builtin_amdgcn_mfma_f32_16x16x32_bf16(pf1, vf1, oacc[nd], 0, 0, 0);
            }
        }

        // ---- normalize + write ----
        const size_t orow = (size_t)(b * 1024 + qt * 64 + wave * 16);
#pragma unroll
        for (int r = 0; r < 4; ++r) {
            const float inv = 1.0f / lrun[r];
#pragma unroll
            for (int nd = 0; nd < 4; ++nd)
                O[(orow + rb + r) * 1024 + h * 64 + nd * 16 + lr] = f2b(oacc[nd][r] * inv);
        }
    }
}

extern "C" void kernel_launch(void* const* d_in, const int* in_sizes, int n_in,
                              void* d_out, int out_size, void* d_ws, size_t ws_size,
                              hipStream_t stream) {
    const float* x    = (const float*)d_in[0];
    const float* ctx  = (const float*)d_in[1];
    const int*   len  = (const int*)d_in[2];
    const float* Wq   = (const float*)d_in[3];
    const float* Wkv  = (const float*)d_in[4];
    const float* Wout = (const float*)d_in[5];
    const float* bout = (const float*)d_in[6];
    float* out = (float*)d_out;

    char* w = (char*)d_ws;
    unsigned short* xb   = (unsigned short*)w; w += (size_t)8192 * 1024 * 2;
    unsigned short* cb   = (unsigned short*)w; w += (size_t)8192 * 1024 * 2;
    unsigned short* qb   = (unsigned short*)w; w += (size_t)8192 * 1024 * 2;
    unsigned short* kvb  = (unsigned short*)w; w += (size_t)8192 * 2048 * 2;
    unsigned short* aob  = (unsigned short*)w; w += (size_t)8192 * 1024 * 2;
    unsigned short* wqt  = (unsigned short*)w; w += (size_t)1024 * 1024 * 2;
    unsigned short* wkvt = (unsigned short*)w; w += (size_t)2048 * 1024 * 2;
    unsigned short* wot  = (unsigned short*)w; w += (size_t)1024 * 1024 * 2;
    unsigned int*   ctr  = (unsigned int*)w;   w += 256;

    hipMemsetAsync(ctr, 0, sizeof(unsigned int), stream);

    cast_f32_to_bf16<<<2048, 256, 0, stream>>>(x,   xb, 8192 * 1024);
    cast_f32_to_bf16<<<2048, 256, 0, stream>>>(ctx, cb, 8192 * 1024);
    dim3 tb(32, 8);
    transpose_cast<<<dim3(32, 32), tb, 0, stream>>>(Wq,   wqt,  1024, 1024);
    transpose_cast<<<dim3(64, 32), tb, 0, stream>>>(Wkv,  wkvt, 1024, 2048);
    transpose_cast<<<dim3(32, 32), tb, 0, stream>>>(Wout, wot,  1024, 1024);

    gemm_bt<0><<<512,  256, 0, stream>>>(xb, wqt,  (void*)qb,  nullptr, 8192, 1024, 1024);
    gemm_bt<0><<<1024, 256, 0, stream>>>(cb, wkvt, (void*)kvb, nullptr, 8192, 2048, 1024);
    attn_fused<<<1280, 256, 0, stream>>>(qb, kvb, len, aob, ctr);
    gemm_bt<1><<<512,  256, 0, stream>>>(aob, wot, (void*)out, bout, 8192, 1024, 1024);
}

// Round 8
// 329.640 us; speedup vs baseline: 1.1719x; 1.0217x over previous
//
#include <hip/hip_runtime.h>
#include <hip/hip_bf16.h>
#include <math.h>

typedef __attribute__((ext_vector_type(4))) float f32x4;
typedef __attribute__((ext_vector_type(8))) short bf16x8;

#define DEVI __device__ __forceinline__
#define GLBP(p) ((const __attribute__((address_space(1))) void*)(p))
#define LDSP(p) ((__attribute__((address_space(3))) void*)(p))

DEVI unsigned short f2b(float x) {
    __hip_bfloat16 b = __float2bfloat16(x);
    return *reinterpret_cast<unsigned short*>(&b);
}

// ---------------- cast f32 -> bf16, vectorized ----------------
__global__ void cast_f32_to_bf16(const float* __restrict__ in,
                                 unsigned short* __restrict__ out, int n) {
    int stride = gridDim.x * blockDim.x;
    for (int i = blockIdx.x * blockDim.x + threadIdx.x; i * 4 < n; i += stride) {
        float4 v = reinterpret_cast<const float4*>(in)[i];
        ushort4 o;
        o.x = f2b(v.x); o.y = f2b(v.y); o.z = f2b(v.z); o.w = f2b(v.w);
        reinterpret_cast<ushort4*>(out)[i] = o;
    }
}

// ------------- transpose+cast: f32 [R][C] -> bf16 [C][R] -------------
__global__ void transpose_cast(const float* __restrict__ in,
                               unsigned short* __restrict__ out, int R, int C) {
    __shared__ float t[32][33];
    int bc = blockIdx.x * 32, br = blockIdx.y * 32;
    int x = threadIdx.x, y = threadIdx.y;   // block (32,8)
#pragma unroll
    for (int j = 0; j < 32; j += 8)
        t[y + j][x] = in[(size_t)(br + y + j) * C + bc + x];
    __syncthreads();
#pragma unroll
    for (int j = 0; j < 32; j += 8)
        out[(size_t)(bc + y + j) * R + br + x] = f2b(t[x][y + j]);
}

// ------------- GEMM: C[M,N] = A[M,K] * B[N,K]^T (bf16 in, bf16/f32 out) -------------
template<int OUTF32>
__global__ __launch_bounds__(256, 2)
void gemm_bt(const unsigned short* __restrict__ A,
             const unsigned short* __restrict__ B,
             void* __restrict__ Cp, const float* __restrict__ bias,
             int M, int N, int K) {
    __shared__ unsigned short As[128 * 32];
    __shared__ unsigned short Bs[128 * 32];
    const int tid  = threadIdx.x;
    const int wave = tid >> 6;
    const int lane = tid & 63;
    const int nbn  = N >> 7;
    const int bm   = blockIdx.x / nbn;
    const int bn   = blockIdx.x - bm * nbn;

    const int lr  = lane & 15;
    const int lk8 = (lane >> 4) << 3;
    const int wr  = (wave >> 1) * 64;
    const int wc  = (wave & 1) * 64;

    const unsigned short* ag = A + (size_t)(bm * 128 + (tid >> 2)) * K + ((tid & 3) << 3);
    const unsigned short* bg = B + (size_t)(bn * 128 + (tid >> 2)) * K + ((tid & 3) << 3);
    unsigned short* asd = As + wave * 512;   // wave-uniform LDS dest
    unsigned short* bsd = Bs + wave * 512;

    f32x4 acc[4][4];
#pragma unroll
    for (int m = 0; m < 4; ++m)
#pragma unroll
        for (int n = 0; n < 4; ++n)
            acc[m][n] = (f32x4){0.f, 0.f, 0.f, 0.f};

    for (int k0 = 0; k0 < K; k0 += 32) {
        __builtin_amdgcn_global_load_lds(GLBP(ag + k0),                    LDSP(asd),        16, 0, 0);
        __builtin_amdgcn_global_load_lds(GLBP(ag + (size_t)64 * K + k0),   LDSP(asd + 2048), 16, 0, 0);
        __builtin_amdgcn_global_load_lds(GLBP(bg + k0),                    LDSP(bsd),        16, 0, 0);
        __builtin_amdgcn_global_load_lds(GLBP(bg + (size_t)64 * K + k0),   LDSP(bsd + 2048), 16, 0, 0);
        __syncthreads();
        bf16x8 af[4], bfr[4];
#pragma unroll
        for (int m = 0; m < 4; ++m)
            af[m] = *reinterpret_cast<const bf16x8*>(&As[(wr + m * 16 + lr) * 32 + lk8]);
#pragma unroll
        for (int n = 0; n < 4; ++n)
            bfr[n] = *reinterpret_cast<const bf16x8*>(&Bs[(wc + n * 16 + lr) * 32 + lk8]);
#pragma unroll
        for (int m = 0; m < 4; ++m)
#pragma unroll
            for (int n = 0; n < 4; ++n)
                acc[m][n] = __builtin_amdgcn_mfma_f32_16x16x32_bf16(af[m], bfr[n], acc[m][n], 0, 0, 0);
        __syncthreads();
    }

    const int rb = (lane >> 4) << 2;
    if (OUTF32) {
        float* C = reinterpret_cast<float*>(Cp);
#pragma unroll
        for (int m = 0; m < 4; ++m)
#pragma unroll
            for (int n = 0; n < 4; ++n) {
                const int col = bn * 128 + wc + n * 16 + lr;
                const float bv = bias[col];
#pragma unroll
                for (int r = 0; r < 4; ++r) {
                    const int row = bm * 128 + wr + m * 16 + rb + r;
                    C[(size_t)row * N + col] = acc[m][n][r] + bv;
                }
            }
    } else {
        unsigned short* C = reinterpret_cast<unsigned short*>(Cp);
#pragma unroll
        for (int m = 0; m < 4; ++m)
#pragma unroll
            for (int n = 0; n < 4; ++n) {
                const int col = bn * 128 + wc + n * 16 + lr;
#pragma unroll
                for (int r = 0; r < 4; ++r) {
                    const int row = bm * 128 + wr + m * 16 + rb + r;
                    C[(size_t)row * N + col] = f2b(acc[m][n][r]);
                }
            }
    }
}

// ------------- fused flash attention with key-length masking (v6) -------------
// v6 change: PARTITIONED work queues. Round-7's single queue fixed the skew
// tail (occ 16->38%) but scrambled (b,h)->XCD affinity: KV panels bounced
// across all 8 non-coherent L2s (FETCH 16->88MB, per-tile KV latency went
// HBM-class, waves stalled). Now 8 queues keyed by bid&7 (= XCD id under
// round-robin dispatch); queue k owns items with h in {k, k+8}:
//  - per-queue work = 32*sum_b ceil(L_b/64)  -> EXACTLY equal across queues
//  - per-XCD KV working set = 16 panels * 256KB = 4MB = one L2
//  - consecutive items in a queue share a panel (qt fastest) -> temporally hot
// Inner loop identical to rounds 5/7 (rotation Vt + distance-1 reg prefetch).
__global__ __launch_bounds__(256, 5)
void attn_fused(const unsigned short* __restrict__ Q,   // [8192][1024]
                const unsigned short* __restrict__ KV,  // [8192][2048] (k | v)
                const int* __restrict__ lengths,
                unsigned short* __restrict__ O,         // [8192][1024]
                unsigned int* __restrict__ ctrs) {      // 8 counters, 64B apart
    __shared__ unsigned short Kl[64 * 72];      // [key][d], stride 72
    __shared__ unsigned short Vt[64 * 72];      // [d][rot(key)], stride 72
    __shared__ unsigned short Pl[4][16 * 72];   // per-wave [q][key], stride 72
    __shared__ int s_item;

    const int tid  = threadIdx.x;
    const int wave = tid >> 6;
    const int lane = tid & 63;
    const int part = blockIdx.x & 7;            // queue / XCD-affinity key

    const int lr  = lane & 15;
    const int g   = lane >> 4;
    const int lk8 = g << 3;     // 0,8,16,24
    const int rb  = g << 2;     // 0,4,8,12

    // staging assignment (coalesced): key0 = tid>>3 (+32 rep1), dseg=(tid&7)*8
    const int skey = tid >> 3;          // 0..31
    const int sds  = (tid & 7) << 3;    // 0..56
    const int vcol0 = (skey + sds) & 63;        // Vt rotated col, rep 0
    const int vcol1 = (skey + 32 + sds) & 63;   // rep 1

    while (true) {
        __syncthreads();   // prev item's s_item reads + Vt/Pl reads done
        if (tid == 0) s_item = (int)atomicAdd(&ctrs[part * 16], 1u);
        __syncthreads();
        const int idx = s_item;
        if (idx >= 256) break;   // 256 items per partition

        // decode within partition: qt fastest (panel stays hot), then b, then h-high
        const int qt = idx & 15;
        const int b  = (idx >> 4) & 7;
        const int h  = ((idx >> 7) & 1) * 8 + part;
        const int L  = lengths[b];

        const size_t kvbase = (size_t)(b * 1024) * 2048 + h * 64;

        // Q fragments (A-operand: row=lane&15, k=(lane>>4)*8+j within 32-slice)
        const size_t qrow = (size_t)(b * 1024 + qt * 64 + wave * 16 + lr);
        bf16x8 qf[2];
        qf[0] = *reinterpret_cast<const bf16x8*>(&Q[qrow * 1024 + h * 64 + lk8]);
        qf[1] = *reinterpret_cast<const bf16x8*>(&Q[qrow * 1024 + h * 64 + 32 + lk8]);

        f32x4 oacc[4];
#pragma unroll
        for (int nd = 0; nd < 4; ++nd) oacc[nd] = (f32x4){0.f, 0.f, 0.f, 0.f};
        float mrun[4] = {-3.0e38f, -3.0e38f, -3.0e38f, -3.0e38f};
        float lrun[4] = {0.f, 0.f, 0.f, 0.f};

        const int ntiles = (L + 63) >> 6;

        // ---- prologue: load tile 0 K/V into regs (coalesced) ----
        bf16x8 kreg[2], vreg[2];
        {
            const size_t r0 = kvbase + (size_t)(skey)      * 2048 + sds;
            const size_t r1 = kvbase + (size_t)(skey + 32) * 2048 + sds;
            kreg[0] = *reinterpret_cast<const bf16x8*>(&KV[r0]);
            kreg[1] = *reinterpret_cast<const bf16x8*>(&KV[r1]);
            vreg[0] = *reinterpret_cast<const bf16x8*>(&KV[r0 + 1024]);
            vreg[1] = *reinterpret_cast<const bf16x8*>(&KV[r1 + 1024]);
        }

        for (int t = 0; t < ntiles; ++t) {
            __syncthreads();   // PV(t-1) readers done before overwrite

            // ---- write staged regs (tile t) to LDS ----
            *reinterpret_cast<bf16x8*>(&Kl[skey * 72 + sds])        = kreg[0];
            *reinterpret_cast<bf16x8*>(&Kl[(skey + 32) * 72 + sds]) = kreg[1];
#pragma unroll
            for (int j = 0; j < 8; ++j)
                Vt[(sds + j) * 72 + vcol0] = (unsigned short)vreg[0][j];
#pragma unroll
            for (int j = 0; j < 8; ++j)
                Vt[(sds + j) * 72 + vcol1] = (unsigned short)vreg[1][j];

            // ---- issue tile t+1 loads (latency hidden under compute(t)) ----
            {
                const int j0n = (t + 1) * 64;
                int r0i = j0n + skey;        r0i = r0i > 1023 ? 1023 : r0i;
                int r1i = j0n + skey + 32;   r1i = r1i > 1023 ? 1023 : r1i;
                const size_t r0 = kvbase + (size_t)r0i * 2048 + sds;
                const size_t r1 = kvbase + (size_t)r1i * 2048 + sds;
                kreg[0] = *reinterpret_cast<const bf16x8*>(&KV[r0]);
                kreg[1] = *reinterpret_cast<const bf16x8*>(&KV[r1]);
                vreg[0] = *reinterpret_cast<const bf16x8*>(&KV[r0 + 1024]);
                vreg[1] = *reinterpret_cast<const bf16x8*>(&KV[r1 + 1024]);
            }

            __syncthreads();   // tile t fully staged

            const int j0 = t * 64;

            // ---- S = Q K^T from Kl ----
            f32x4 sacc[4];
#pragma unroll
            for (int n = 0; n < 4; ++n) sacc[n] = (f32x4){0.f, 0.f, 0.f, 0.f};
#pragma unroll
            for (int n = 0; n < 4; ++n) {
                bf16x8 kf0 = *reinterpret_cast<const bf16x8*>(&Kl[(n * 16 + lr) * 72 + lk8]);
                bf16x8 kf1 = *reinterpret_cast<const bf16x8*>(&Kl[(n * 16 + lr) * 72 + 32 + lk8]);
                sacc[n] = __builtin_amdgcn_mfma_f32_16x16x32_bf16(qf[0], kf0, sacc[n], 0, 0, 0);
                sacc[n] = __builtin_amdgcn_mfma_f32_16x16x32_bf16(qf[1], kf1, sacc[n], 0, 0, 0);
            }

            // ---- scale + mask ----
            float sv[4][4];
#pragma unroll
            for (int n = 0; n < 4; ++n)
#pragma unroll
                for (int r = 0; r < 4; ++r) {
                    const int key = j0 + n * 16 + lr;
                    sv[n][r] = (key < L) ? sacc[n][r] * 0.125f : -3.0e38f;
                }

            // ---- online softmax (row r of 16-lane group) ----
            float alpha[4], psum[4];
#pragma unroll
            for (int r = 0; r < 4; ++r) {
                float tm = fmaxf(fmaxf(sv[0][r], sv[1][r]), fmaxf(sv[2][r], sv[3][r]));
#pragma unroll
                for (int off = 1; off < 16; off <<= 1)
                    tm = fmaxf(tm, __shfl_xor(tm, off));
                const float mn = fmaxf(mrun[r], tm);
                alpha[r] = __expf(mrun[r] - mn);
                mrun[r] = mn;
                psum[r] = 0.f;
            }
            float pv[4][4];
#pragma unroll
            for (int n = 0; n < 4; ++n)
#pragma unroll
                for (int r = 0; r < 4; ++r) {
                    const float p = __expf(sv[n][r] - mrun[r]);
                    pv[n][r] = p;
                    psum[r] += p;
                }
#pragma unroll
            for (int r = 0; r < 4; ++r) {
#pragma unroll
                for (int off = 1; off < 16; off <<= 1)
                    psum[r] += __shfl_xor(psum[r], off);
                lrun[r] = lrun[r] * alpha[r] + psum[r];
            }
#pragma unroll
            for (int nd = 0; nd < 4; ++nd)
#pragma unroll
                for (int r = 0; r < 4; ++r)
                    oacc[nd][r] *= alpha[r];

            // ---- P -> per-wave LDS (same-wave dep, no barrier) ----
#pragma unroll
            for (int n = 0; n < 4; ++n)
#pragma unroll
                for (int r = 0; r < 4; ++r)
                    Pl[wave][(rb + r) * 72 + n * 16 + lr] = f2b(pv[n][r]);

            // ---- O += P V (Vt read with rotation) ----
            bf16x8 pf0 = *reinterpret_cast<const bf16x8*>(&Pl[wave][lr * 72 + lk8]);
            bf16x8 pf1 = *reinterpret_cast<const bf16x8*>(&Pl[wave][lr * 72 + 32 + lk8]);
#pragma unroll
            for (int nd = 0; nd < 4; ++nd) {
                const int d = nd * 16 + lr;
                const int c0 = (lk8 + (d & 56)) & 63;
                const int c1 = ((32 + lk8) + (d & 56)) & 63;
                bf16x8 vf0 = *reinterpret_cast<const bf16x8*>(&Vt[d * 72 + c0]);
                bf16x8 vf1 = *reinterpret_cast<const bf16x8*>(&Vt[d * 72 + c1]);
                oacc[nd] = __builtin_amdgcn_mfma_f32_16x16x32_bf16(pf0, vf0, oacc[nd], 0, 0, 0);
                oacc[nd] = __builtin_amdgcn_mfma_f32_16x16x32_bf16(pf1, vf1, oacc[nd], 0, 0, 0);
            }
        }

        // ---- normalize + write ----
        const size_t orow = (size_t)(b * 1024 + qt * 64 + wave * 16);
#pragma unroll
        for (int r = 0; r < 4; ++r) {
            const float inv = 1.0f / lrun[r];
#pragma unroll
            for (int nd = 0; nd < 4; ++nd)
                O[(orow + rb + r) * 1024 + h * 64 + nd * 16 + lr] = f2b(oacc[nd][r] * inv);
        }
    }
}

extern "C" void kernel_launch(void* const* d_in, const int* in_sizes, int n_in,
                              void* d_out, int out_size, void* d_ws, size_t ws_size,
                              hipStream_t stream) {
    const float* x    = (const float*)d_in[0];
    const float* ctx  = (const float*)d_in[1];
    const int*   len  = (const int*)d_in[2];
    const float* Wq   = (const float*)d_in[3];
    const float* Wkv  = (const float*)d_in[4];
    const float* Wout = (const float*)d_in[5];
    const float* bout = (const float*)d_in[6];
    float* out = (float*)d_out;

    char* w = (char*)d_ws;
    unsigned short* xb   = (unsigned short*)w; w += (size_t)8192 * 1024 * 2;
    unsigned short* cb   = (unsigned short*)w; w += (size_t)8192 * 1024 * 2;
    unsigned short* qb   = (unsigned short*)w; w += (size_t)8192 * 1024 * 2;
    unsigned short* kvb  = (unsigned short*)w; w += (size_t)8192 * 2048 * 2;
    unsigned short* aob  = (unsigned short*)w; w += (size_t)8192 * 1024 * 2;
    unsigned short* wqt  = (unsigned short*)w; w += (size_t)1024 * 1024 * 2;
    unsigned short* wkvt = (unsigned short*)w; w += (size_t)2048 * 1024 * 2;
    unsigned short* wot  = (unsigned short*)w; w += (size_t)1024 * 1024 * 2;
    unsigned int*   ctrs = (unsigned int*)w;   w += 1024;   // 8 counters, 64B apart

    hipMemsetAsync(ctrs, 0, 512, stream);

    cast_f32_to_bf16<<<2048, 256, 0, stream>>>(x,   xb, 8192 * 1024);
    cast_f32_to_bf16<<<2048, 256, 0, stream>>>(ctx, cb, 8192 * 1024);
    dim3 tb(32, 8);
    transpose_cast<<<dim3(32, 32), tb, 0, stream>>>(Wq,   wqt,  1024, 1024);
    transpose_cast<<<dim3(64, 32), tb, 0, stream>>>(Wkv,  wkvt, 1024, 2048);
    transpose_cast<<<dim3(32, 32), tb, 0, stream>>>(Wout, wot,  1024, 1024);

    gemm_bt<0><<<512,  256, 0, stream>>>(xb, wqt,  (void*)qb,  nullptr, 8192, 1024, 1024);
    gemm_bt<0><<<1024, 256, 0, stream>>>(cb, wkvt, (void*)kvb, nullptr, 8192, 2048, 1024);
    attn_fused<<<1280, 256, 0, stream>>>(qb, kvb, len, aob, ctrs);
    gemm_bt<1><<<512,  256, 0, stream>>>(aob, wot, (void*)out, bout, 8192, 1024, 1024);
}